// Round 1
// baseline (287.728 us; speedup 1.0000x reference)
//
#include <hip/hip_runtime.h>
#include <hip/hip_bf16.h>

#define B_ 32
#define T_ 256
#define NIN_ 128
#define H_ 32
#define NOUT_ 128
#define R_ (B_ * T_)   // 8192 rows

// ---------------------------------------------------------------------------
// Kernel 1: y[row][h] = dot(x[row,:], W_in[h,:]) + b_in[h]
// thread per (row, h) : R_*H_ = 262144 threads
// ---------------------------------------------------------------------------
__global__ void k_y(const float* __restrict__ x,
                    const float* __restrict__ W_in,
                    const float* __restrict__ b_in,
                    float* __restrict__ y) {
    int idx = blockIdx.x * blockDim.x + threadIdx.x;
    if (idx >= R_ * H_) return;
    int row = idx >> 5;
    int hh  = idx & 31;
    const float4* x4 = reinterpret_cast<const float4*>(x + row * NIN_);
    const float4* w4 = reinterpret_cast<const float4*>(W_in + hh * NIN_);
    float acc = b_in[hh];
    #pragma unroll
    for (int k = 0; k < NIN_ / 4; ++k) {
        float4 xv = x4[k];
        float4 wv = w4[k];
        acc += xv.x * wv.x + xv.y * wv.y + xv.z * wv.z + xv.w * wv.w;
    }
    y[idx] = acc;
}

// ---------------------------------------------------------------------------
// Kernel 2: h[row][g] = dot(y[row,:], W_h[g,:]) ; o[row][g] = dot(y[row,:], W_o[g,:])
// thread per (row, g)
// ---------------------------------------------------------------------------
__global__ void k_ho(const float* __restrict__ y,
                     const float* __restrict__ W_h,
                     const float* __restrict__ W_o,
                     float* __restrict__ h,
                     float* __restrict__ o) {
    int idx = blockIdx.x * blockDim.x + threadIdx.x;
    if (idx >= R_ * H_) return;
    int row = idx >> 5;
    int g   = idx & 31;
    const float4* y4  = reinterpret_cast<const float4*>(y + row * H_);
    const float4* wh4 = reinterpret_cast<const float4*>(W_h + g * H_);
    const float4* wo4 = reinterpret_cast<const float4*>(W_o + g * H_);
    float ah = 0.f, ao = 0.f;
    #pragma unroll
    for (int k = 0; k < H_ / 4; ++k) {
        float4 yv = y4[k];
        float4 hv = wh4[k];
        float4 ov = wo4[k];
        ah += yv.x * hv.x + yv.y * hv.y + yv.z * hv.z + yv.w * hv.w;
        ao += yv.x * ov.x + yv.y * ov.y + yv.z * ov.z + yv.w * ov.w;
    }
    h[idx] = ah;
    o[idx] = ao;
}

// ---------------------------------------------------------------------------
// Kernel 3: per (b,i) block of 256 threads:
//   e_j = sum_h V[h] * tanh(h_i[h] + o_j[h])        (thread j)
//   att = e - logsumexp(e)                          (block reduce)
//   ctx[h] = sum_j att_j * y[b,j,h]                 (chunked partial sums)
//   out[b,i,oc] = b_out[oc] + sum_h W_out[oc,h]*ctx[h]
// ---------------------------------------------------------------------------
__global__ void __launch_bounds__(256) k_att(
        const float* __restrict__ y,
        const float* __restrict__ h,
        const float* __restrict__ o,
        const float* __restrict__ V,
        const float* __restrict__ W_out,
        const float* __restrict__ b_out,
        float* __restrict__ out) {
    __shared__ float hi[H_];
    __shared__ float Vs[H_];
    __shared__ float att[T_];
    __shared__ float red[8];
    __shared__ float cpart[8][H_];
    __shared__ float ctx[H_];

    const int bi = blockIdx.x;           // 0 .. B*T-1
    const int bb = bi >> 8;              // batch
    const int ii = bi & 255;             // query index i
    const int t  = threadIdx.x;          // 0..255 ; doubles as key index j

    if (t < H_) {
        hi[t] = h[(bb * T_ + ii) * H_ + t];
        Vs[t] = V[t];
    }
    __syncthreads();

    // ---- e_j ----
    const float* oj = o + (bb * T_ + t) * H_;
    float e = 0.f;
    #pragma unroll
    for (int k = 0; k < H_; ++k) {
        e += Vs[k] * tanhf(hi[k] + oj[k]);
    }

    // ---- block max ----
    float m = e;
    #pragma unroll
    for (int off = 1; off < 64; off <<= 1)
        m = fmaxf(m, __shfl_xor(m, off));
    if ((t & 63) == 0) red[t >> 6] = m;
    __syncthreads();
    m = fmaxf(fmaxf(red[0], red[1]), fmaxf(red[2], red[3]));

    // ---- block sum of exp(e-m) ----
    float s = expf(e - m);
    float ssum = s;
    #pragma unroll
    for (int off = 1; off < 64; off <<= 1)
        ssum += __shfl_xor(ssum, off);
    if ((t & 63) == 0) red[4 + (t >> 6)] = ssum;
    __syncthreads();
    float S = (red[4] + red[5]) + (red[6] + red[7]);
    float lse = m + logf(S);

    att[t] = e - lse;   // log-probabilities (faithful to reference)
    __syncthreads();

    // ---- context: ctx[h] = sum_j att[j] * y[b,j,h] ----
    {
        int hh    = t & 31;
        int chunk = t >> 5;      // 8 chunks of 32 j's
        float acc = 0.f;
        #pragma unroll
        for (int jj = 0; jj < 32; ++jj) {
            int j = (chunk << 5) + jj;
            acc += att[j] * y[(bb * T_ + j) * H_ + hh];
        }
        cpart[chunk][hh] = acc;
    }
    __syncthreads();
    if (t < H_) {
        float acc = 0.f;
        #pragma unroll
        for (int c = 0; c < 8; ++c) acc += cpart[c][t];
        ctx[t] = acc;
    }
    __syncthreads();

    // ---- output projection: 128 outputs ----
    if (t < NOUT_) {
        const float4* w4 = reinterpret_cast<const float4*>(W_out + t * H_);
        float acc = b_out[t];
        #pragma unroll
        for (int k = 0; k < H_ / 4; ++k) {
            float4 wv = w4[k];
            float4 cv = *reinterpret_cast<const float4*>(&ctx[k * 4]);
            acc += wv.x * cv.x + wv.y * cv.y + wv.z * cv.z + wv.w * cv.w;
        }
        out[(bb * T_ + ii) * NOUT_ + t] = acc;
    }
}

// ---------------------------------------------------------------------------
extern "C" void kernel_launch(void* const* d_in, const int* in_sizes, int n_in,
                              void* d_out, int out_size, void* d_ws, size_t ws_size,
                              hipStream_t stream) {
    const float* x     = (const float*)d_in[0];
    const float* W_in  = (const float*)d_in[1];
    const float* b_in  = (const float*)d_in[2];
    const float* W_h   = (const float*)d_in[3];
    const float* W_o   = (const float*)d_in[4];
    const float* V     = (const float*)d_in[5];
    const float* W_out = (const float*)d_in[6];
    const float* b_out = (const float*)d_in[7];
    float* out = (float*)d_out;

    // workspace layout: y | h | o  (each R_*H_ floats = 1 MB)
    float* y = (float*)d_ws;
    float* h = y + R_ * H_;
    float* o = h + R_ * H_;

    {   // y = x @ W_in^T + b_in
        int n = R_ * H_;
        k_y<<<(n + 255) / 256, 256, 0, stream>>>(x, W_in, b_in, y);
    }
    {   // h, o projections
        int n = R_ * H_;
        k_ho<<<(n + 255) / 256, 256, 0, stream>>>(y, W_h, W_o, h, o);
    }
    {   // attention + output
        k_att<<<R_, 256, 0, stream>>>(y, h, o, V, W_out, b_out, out);
    }
}

// Round 2
// 87.425 us; speedup vs baseline: 3.2911x; 3.2911x over previous
//
#include <hip/hip_runtime.h>
#include <hip/hip_bf16.h>

#define B_ 32
#define T_ 256
#define NIN_ 128
#define H_ 32
#define NOUT_ 128
#define R_ (B_ * T_)   // 8192 rows

// tanh(x) = 1 - 2/(exp(2x)+1), branch-free, saturates correctly:
//   exp2 -> +inf => rcp -> 0   => +1
//   exp2 -> 0    => rcp(1) = 1 => -1
__device__ __forceinline__ float tanh_fast(float x) {
    float ex = __builtin_amdgcn_exp2f(x * 2.88539008177792681472f); // 2*log2(e)
    float r  = __builtin_amdgcn_rcpf(ex + 1.0f);
    return fmaf(-2.0f, r, 1.0f);
}

// ---------------------------------------------------------------------------
// Fused kernel 1: per block = 8 rows x 32 h.
//   y[row][h] = dot(x[row,:], W_in[h,:]) + b_in[h]   (stage in LDS)
//   h[row][g] = dot(y[row,:], W_h[g,:])
//   o[row][g] = dot(y[row,:], W_o[g,:])
// ---------------------------------------------------------------------------
__global__ void __launch_bounds__(256) k_yho(
        const float* __restrict__ x,
        const float* __restrict__ W_in,
        const float* __restrict__ b_in,
        const float* __restrict__ W_h,
        const float* __restrict__ W_o,
        float* __restrict__ y,
        float* __restrict__ h,
        float* __restrict__ o) {
    __shared__ float ys[8][H_];
    const int t   = threadIdx.x;
    const int r   = t >> 5;              // local row 0..7
    const int hh  = t & 31;
    const int row = blockIdx.x * 8 + r;

    // y = x @ W_in^T + b_in
    {
        const float4* x4 = reinterpret_cast<const float4*>(x + row * NIN_);
        const float4* w4 = reinterpret_cast<const float4*>(W_in + hh * NIN_);
        float acc = b_in[hh];
        #pragma unroll
        for (int k = 0; k < NIN_ / 4; ++k) {
            float4 xv = x4[k];
            float4 wv = w4[k];
            acc += xv.x * wv.x + xv.y * wv.y + xv.z * wv.z + xv.w * wv.w;
        }
        ys[r][hh] = acc;
        y[row * H_ + hh] = acc;
    }
    __syncthreads();

    // h, o projections from the LDS-staged y row
    {
        const float4* y4  = reinterpret_cast<const float4*>(&ys[r][0]);
        const float4* wh4 = reinterpret_cast<const float4*>(W_h + hh * H_);
        const float4* wo4 = reinterpret_cast<const float4*>(W_o + hh * H_);
        float ah = 0.f, ao = 0.f;
        #pragma unroll
        for (int k = 0; k < H_ / 4; ++k) {
            float4 yv = y4[k];
            float4 hv = wh4[k];
            float4 ov = wo4[k];
            ah += yv.x * hv.x + yv.y * hv.y + yv.z * hv.z + yv.w * hv.w;
            ao += yv.x * ov.x + yv.y * ov.y + yv.z * ov.z + yv.w * ov.w;
        }
        h[row * H_ + hh] = ah;
        o[row * H_ + hh] = ao;
    }
}

// ---------------------------------------------------------------------------
// Kernel 2: per (b,i) block of 256 threads:
//   e_j = sum_h V[h] * tanh(h_i[h] + o_j[h])        (thread j)
//   att = e - logsumexp(e)                          (block reduce)
//   ctx[h] = sum_j att_j * y[b,j,h]                 (chunked partial sums)
//   out[b,i,oc] = b_out[oc] + sum_h W_out[oc,h]*ctx[h]
// ---------------------------------------------------------------------------
__global__ void __launch_bounds__(256) k_att(
        const float* __restrict__ y,
        const float* __restrict__ h,
        const float* __restrict__ o,
        const float* __restrict__ V,
        const float* __restrict__ W_out,
        const float* __restrict__ b_out,
        float* __restrict__ out) {
    __shared__ float hi[H_];
    __shared__ float Vs[H_];
    __shared__ float att[T_];
    __shared__ float red[8];
    __shared__ float cpart[8][H_];
    __shared__ float ctx[H_];

    const int bi = blockIdx.x;           // 0 .. B*T-1
    const int bb = bi >> 8;              // batch
    const int ii = bi & 255;             // query index i
    const int t  = threadIdx.x;          // 0..255 ; doubles as key index j

    if (t < H_) {
        hi[t] = h[(bb * T_ + ii) * H_ + t];
        Vs[t] = V[t];
    }
    __syncthreads();

    // ---- e_j = sum_h V[h] * tanh(hi[h] + o_j[h]) ----
    const float4* o4 = reinterpret_cast<const float4*>(o + (bb * T_ + t) * H_);
    float e = 0.f;
    #pragma unroll
    for (int k4 = 0; k4 < H_ / 4; ++k4) {
        float4 ov = o4[k4];
        e += Vs[k4 * 4 + 0] * tanh_fast(hi[k4 * 4 + 0] + ov.x);
        e += Vs[k4 * 4 + 1] * tanh_fast(hi[k4 * 4 + 1] + ov.y);
        e += Vs[k4 * 4 + 2] * tanh_fast(hi[k4 * 4 + 2] + ov.z);
        e += Vs[k4 * 4 + 3] * tanh_fast(hi[k4 * 4 + 3] + ov.w);
    }

    // ---- block max ----
    float m = e;
    #pragma unroll
    for (int off = 1; off < 64; off <<= 1)
        m = fmaxf(m, __shfl_xor(m, off));
    if ((t & 63) == 0) red[t >> 6] = m;
    __syncthreads();
    m = fmaxf(fmaxf(red[0], red[1]), fmaxf(red[2], red[3]));

    // ---- block sum of exp(e-m) ----
    float s = __builtin_amdgcn_exp2f((e - m) * 1.44269504088896341f);
    float ssum = s;
    #pragma unroll
    for (int off = 1; off < 64; off <<= 1)
        ssum += __shfl_xor(ssum, off);
    if ((t & 63) == 0) red[4 + (t >> 6)] = ssum;
    __syncthreads();
    float S = (red[4] + red[5]) + (red[6] + red[7]);
    float lse = m + __builtin_amdgcn_logf(S) * 0.69314718055994531f;

    att[t] = e - lse;   // log-probabilities (faithful to reference)
    __syncthreads();

    // ---- context: ctx[h] = sum_j att[j] * y[b,j,h] ----
    {
        int hh    = t & 31;
        int chunk = t >> 5;      // 8 chunks of 32 j's
        float acc = 0.f;
        #pragma unroll
        for (int jj = 0; jj < 32; ++jj) {
            int j = (chunk << 5) + jj;
            acc += att[j] * y[(bb * T_ + j) * H_ + hh];
        }
        cpart[chunk][hh] = acc;
    }
    __syncthreads();
    if (t < H_) {
        float acc = 0.f;
        #pragma unroll
        for (int c = 0; c < 8; ++c) acc += cpart[c][t];
        ctx[t] = acc;
    }
    __syncthreads();

    // ---- output projection: 128 outputs ----
    if (t < NOUT_) {
        const float4* w4 = reinterpret_cast<const float4*>(W_out + t * H_);
        float acc = b_out[t];
        #pragma unroll
        for (int k = 0; k < H_ / 4; ++k) {
            float4 wv = w4[k];
            float4 cv = *reinterpret_cast<const float4*>(&ctx[k * 4]);
            acc += wv.x * cv.x + wv.y * cv.y + wv.z * cv.z + wv.w * cv.w;
        }
        out[(bb * T_ + ii) * NOUT_ + t] = acc;
    }
}

// ---------------------------------------------------------------------------
extern "C" void kernel_launch(void* const* d_in, const int* in_sizes, int n_in,
                              void* d_out, int out_size, void* d_ws, size_t ws_size,
                              hipStream_t stream) {
    const float* x     = (const float*)d_in[0];
    const float* W_in  = (const float*)d_in[1];
    const float* b_in  = (const float*)d_in[2];
    const float* W_h   = (const float*)d_in[3];
    const float* W_o   = (const float*)d_in[4];
    const float* V     = (const float*)d_in[5];
    const float* W_out = (const float*)d_in[6];
    const float* b_out = (const float*)d_in[7];
    float* out = (float*)d_out;

    // workspace layout: y | h | o  (each R_*H_ floats = 1 MB)
    float* y = (float*)d_ws;
    float* h = y + R_ * H_;
    float* o = h + R_ * H_;

    k_yho<<<R_ / 8, 256, 0, stream>>>(x, W_in, b_in, W_h, W_o, y, h, o);
    k_att<<<R_, 256, 0, stream>>>(y, h, o, V, W_out, b_out, out);
}